// Round 7
// baseline (605.125 us; speedup 1.0000x reference)
//
#include <hip/hip_runtime.h>
#include <hip/hip_bf16.h>

// SphericalAttention on MI355X (gfx950).  ROUND 7: output is FP32 (the
// reference returns float32; the "(bf16,...)" in the test label is template
// text — my rounds 0-6 wrote packed bf16 into an fp32 buffer, which exactly
// reproduces the observed decorrelated absmax 0.1171875, the R1 NaN, and the
// R0 0.0835). Pipeline = round-2 MFMA flash structure (mutually validated
// against the fp32-naive pipeline), with fp32 output stores.
// Inputs fp32; output fp32. N=4096, C=512, nh=8, dh=64.
//
// ws layout (bytes):
//   [0, 64 MiB)      dist fp32 [4096][4096]
//   +64 KiB          per-block (sum,sumsq) double partials [4096][2]
//   +64 B            neg_inv_std scalar (fp32)
//   then bf16: q[8][4096][64], k[8][4096][64], vt[8][64][4096],
//              att[4096][512], xb[4096][512], wqb[1536][512], wob[512][512]

typedef __attribute__((ext_vector_type(8))) short bf16x8;
typedef __attribute__((ext_vector_type(4))) float f32x4;

#define MFMA16(a, b, c) __builtin_amdgcn_mfma_f32_16x16x32_bf16(a, b, c, 0, 0, 0)

__device__ __forceinline__ unsigned short f2b(float f) {
    union { float f; unsigned int i; } v;
    v.f = f;
    unsigned int lsb = (v.i >> 16) & 1u;
    unsigned int r = v.i + 0x7fffu + lsb;   // RNE
    return (unsigned short)(r >> 16);
}

// ---------------------------------------------------------------- fp32 -> bf16
__global__ __launch_bounds__(256) void cvt_kernel(
    const float* __restrict__ in, unsigned short* __restrict__ out, int n) {
    int i = (blockIdx.x * 256 + threadIdx.x) * 4;
    if (i + 3 < n) {
        float4 v = *(const float4*)(in + i);
        ushort4 u;
        u.x = f2b(v.x); u.y = f2b(v.y); u.z = f2b(v.z); u.w = f2b(v.w);
        *(ushort4*)(out + i) = u;
    }
}

// ---------------------------------------------------------------- dist + stats
__global__ __launch_bounds__(256) void dist_kernel(
    const float* __restrict__ lat, const float* __restrict__ lon,
    float* __restrict__ dist, double* __restrict__ partials) {
    __shared__ float sl_i[64], sc_i[64], so_i[64];
    __shared__ float sl_j[64], sc_j[64], so_j[64];
    __shared__ double rs[256], rs2[256];

    int bi = blockIdx.x;
    int i0 = (bi >> 6) << 6;
    int j0 = (bi & 63) << 6;
    int tid = threadIdx.x;

    if (tid < 64) {
        float la = lat[i0 + tid];
        sl_i[tid] = la; sc_i[tid] = cosf(la); so_i[tid] = lon[i0 + tid];
    } else if (tid < 128) {
        int t = tid - 64;
        float la = lat[j0 + t];
        sl_j[t] = la; sc_j[t] = cosf(la); so_j[t] = lon[j0 + t];
    }
    __syncthreads();

    double s = 0.0, s2 = 0.0;
    int col = tid & 63;
    float latj = sl_j[col], cj = sc_j[col], lonj = so_j[col];
#pragma unroll
    for (int kk = 0; kk < 16; kk++) {
        int row = (kk << 2) + (tid >> 6);
        float dlat = latj - sl_i[row];
        float dlon = lonj - so_i[row];
        float h1 = sinf(0.5f * dlat);
        float h2 = sinf(0.5f * dlon);
        float a = h1 * h1 + sc_i[row] * cj * h2 * h2;
        a = fminf(fmaxf(a, 0.0f), 1.0f);
        float d = 2.0f * asinf(sqrtf(a));
        dist[(size_t)(i0 + row) * 4096 + j0 + col] = d;
        s += (double)d;
        s2 += (double)d * (double)d;
    }
    rs[tid] = s; rs2[tid] = s2;
    __syncthreads();
    for (int off = 128; off > 0; off >>= 1) {
        if (tid < off) { rs[tid] += rs[tid + off]; rs2[tid] += rs2[tid + off]; }
        __syncthreads();
    }
    if (tid == 0) {
        partials[2 * bi] = rs[0];
        partials[2 * bi + 1] = rs2[0];
    }
}

__global__ __launch_bounds__(256) void stats_kernel(
    const double* __restrict__ partials, float* __restrict__ neg_inv_std) {
    __shared__ double rs[256], rs2[256];
    int tid = threadIdx.x;
    double s = 0.0, s2 = 0.0;
    for (int i = tid; i < 4096; i += 256) {
        s += partials[2 * i];
        s2 += partials[2 * i + 1];
    }
    rs[tid] = s; rs2[tid] = s2;
    __syncthreads();
    for (int off = 128; off > 0; off >>= 1) {
        if (tid < off) { rs[tid] += rs[tid + off]; rs2[tid] += rs2[tid + off]; }
        __syncthreads();
    }
    if (tid == 0) {
        double n = 16777216.0;
        double mean = rs[0] / n;
        double var = (rs2[0] - n * mean * mean) / (n - 1.0);  // ddof=1
        *neg_inv_std = (float)(-1.0 / sqrt(var));
    }
}

// ---------------------------------------------------------------- QKV GEMM
// xb [4096,512] bf16 @ wqb^T + b_qkv(fp32) -> q/k [h][n][d], vt [h][d][n]
__global__ __launch_bounds__(256) void qkv_gemm(
    const unsigned short* __restrict__ x, const unsigned short* __restrict__ w,
    const float* __restrict__ b,
    unsigned short* __restrict__ q, unsigned short* __restrict__ k,
    unsigned short* __restrict__ vt) {
    int lane = threadIdx.x & 63, wave = threadIdx.x >> 6;
    int l16 = lane & 15, quad = lane >> 4;
    int m0 = blockIdx.y * 64 + wave * 16;
    int n0 = blockIdx.x * 64;

    const unsigned short* arow = x + (size_t)(m0 + l16) * 512 + quad * 8;
    f32x4 acc[4];
#pragma unroll
    for (int nb = 0; nb < 4; nb++) acc[nb] = (f32x4){0.f, 0.f, 0.f, 0.f};

    for (int k0 = 0; k0 < 512; k0 += 32) {
        bf16x8 af = *(const bf16x8*)(arow + k0);
#pragma unroll
        for (int nb = 0; nb < 4; nb++) {
            bf16x8 bf = *(const bf16x8*)(w + (size_t)(n0 + nb * 16 + l16) * 512 + k0 + quad * 8);
            acc[nb] = MFMA16(af, bf, acc[nb]);
        }
    }
#pragma unroll
    for (int nb = 0; nb < 4; nb++) {
        int j = n0 + nb * 16 + l16;
        float bj = b[j];
        int s = j >> 9;         // 0=q 1=k 2=v
        int rem = j & 511;
        int h = rem >> 6, d = rem & 63;
#pragma unroll
        for (int r = 0; r < 4; r++) {
            int n = m0 + quad * 4 + r;
            unsigned short u = f2b(acc[nb][r] + bj);
            if (s == 0)      q[((size_t)h * 4096 + n) * 64 + d] = u;
            else if (s == 1) k[((size_t)h * 4096 + n) * 64 + d] = u;
            else             vt[((size_t)h * 64 + d) * 4096 + n] = u;
        }
    }
}

// ---------------------------------------------------------------- flash attention
// 1 wave = 16 q-rows; KV tile = 64; per-wave private LDS for P layout transform.
__global__ __launch_bounds__(256) void attn_kernel(
    const unsigned short* __restrict__ q, const unsigned short* __restrict__ k,
    const unsigned short* __restrict__ vt, const float* __restrict__ dist,
    const float* __restrict__ nis_p, unsigned short* __restrict__ att) {
    __shared__ unsigned short pbuf[4][16 * 64];
    int lane = threadIdx.x & 63, wave = threadIdx.x >> 6;
    int l16 = lane & 15, quad = lane >> 4;
    int h = blockIdx.x >> 6;
    int q0 = (blockIdx.x & 63) * 64 + wave * 16;
    float nis = *nis_p;
    const float scale = 0.125f;

    const unsigned short* qbase = q + ((size_t)h * 4096 + q0 + l16) * 64 + quad * 8;
    bf16x8 qf0 = *(const bf16x8*)(qbase);
    bf16x8 qf1 = *(const bf16x8*)(qbase + 32);

    f32x4 o[4];
    float m[4], l[4];
#pragma unroll
    for (int r = 0; r < 4; r++) {
        m[r] = -1e30f; l[r] = 0.f;
        o[0][r] = 0.f; o[1][r] = 0.f; o[2][r] = 0.f; o[3][r] = 0.f;
    }
    unsigned short* pb = pbuf[wave];

    for (int kv0 = 0; kv0 < 4096; kv0 += 64) {
        f32x4 s[4];
#pragma unroll
        for (int cb = 0; cb < 4; cb++) {
            const unsigned short* kbase =
                k + ((size_t)h * 4096 + kv0 + cb * 16 + l16) * 64 + quad * 8;
            bf16x8 kf0 = *(const bf16x8*)(kbase);
            bf16x8 kf1 = *(const bf16x8*)(kbase + 32);
            f32x4 z = (f32x4){0.f, 0.f, 0.f, 0.f};
            z = MFMA16(qf0, kf0, z);
            z = MFMA16(qf1, kf1, z);
            s[cb] = z;
        }
#pragma unroll
        for (int r = 0; r < 4; r++) {
            const float* drow = dist + (size_t)(q0 + quad * 4 + r) * 4096 + kv0 + l16;
#pragma unroll
            for (int cb = 0; cb < 4; cb++)
                s[cb][r] = s[cb][r] * scale + drow[cb * 16] * nis;
        }
        float mt[4];
#pragma unroll
        for (int r = 0; r < 4; r++) {
            float v = fmaxf(fmaxf(s[0][r], s[1][r]), fmaxf(s[2][r], s[3][r]));
#pragma unroll
            for (int off = 1; off < 16; off <<= 1)
                v = fmaxf(v, __shfl_xor(v, off, 64));
            mt[r] = v;
        }
        float al[4];
#pragma unroll
        for (int r = 0; r < 4; r++) {
            float mn = fmaxf(m[r], mt[r]);
            al[r] = __expf(m[r] - mn);
            m[r] = mn;
        }
        float rsum[4] = {0.f, 0.f, 0.f, 0.f};
#pragma unroll
        for (int cb = 0; cb < 4; cb++)
#pragma unroll
            for (int r = 0; r < 4; r++) {
                float p = __expf(s[cb][r] - m[r]);
                s[cb][r] = p;
                rsum[r] += p;
            }
#pragma unroll
        for (int r = 0; r < 4; r++) {
#pragma unroll
            for (int off = 1; off < 16; off <<= 1)
                rsum[r] += __shfl_xor(rsum[r], off, 64);
            l[r] = l[r] * al[r] + rsum[r];
            o[0][r] *= al[r]; o[1][r] *= al[r]; o[2][r] *= al[r]; o[3][r] *= al[r];
        }
        // P (C-layout) -> LDS -> A-operand layout (m120-verified transform)
#pragma unroll
        for (int cb = 0; cb < 4; cb++)
#pragma unroll
            for (int r = 0; r < 4; r++)
                pb[(quad * 4 + r) * 64 + cb * 16 + l16] = f2b(s[cb][r]);
        asm volatile("s_waitcnt lgkmcnt(0)" ::: "memory");
        bf16x8 pf0 = *(const bf16x8*)(pb + l16 * 64 + quad * 8);
        bf16x8 pf1 = *(const bf16x8*)(pb + l16 * 64 + 32 + quad * 8);
#pragma unroll
        for (int db = 0; db < 4; db++) {
            const unsigned short* vbase =
                vt + ((size_t)h * 64 + db * 16 + l16) * 4096 + kv0 + quad * 8;
            bf16x8 vf0 = *(const bf16x8*)(vbase);
            bf16x8 vf1 = *(const bf16x8*)(vbase + 32);
            o[db] = MFMA16(pf0, vf0, o[db]);
            o[db] = MFMA16(pf1, vf1, o[db]);
        }
    }
#pragma unroll
    for (int r = 0; r < 4; r++) {
        float inv = 1.0f / l[r];
        int n = q0 + quad * 4 + r;
#pragma unroll
        for (int db = 0; db < 4; db++)
            att[(size_t)n * 512 + h * 64 + db * 16 + l16] = f2b(o[db][r] * inv);
    }
}

// ---------------------------------------------------------------- output GEMM (fp32 store)
__global__ __launch_bounds__(256) void out_gemm(
    const unsigned short* __restrict__ att, const unsigned short* __restrict__ w,
    const float* __restrict__ b, float* __restrict__ out) {
    int lane = threadIdx.x & 63, wave = threadIdx.x >> 6;
    int l16 = lane & 15, quad = lane >> 4;
    int m0 = blockIdx.y * 64 + wave * 16;
    int n0 = blockIdx.x * 64;

    const unsigned short* arow = att + (size_t)(m0 + l16) * 512 + quad * 8;
    f32x4 acc[4];
#pragma unroll
    for (int nb = 0; nb < 4; nb++) acc[nb] = (f32x4){0.f, 0.f, 0.f, 0.f};

    for (int k0 = 0; k0 < 512; k0 += 32) {
        bf16x8 af = *(const bf16x8*)(arow + k0);
#pragma unroll
        for (int nb = 0; nb < 4; nb++) {
            bf16x8 bf = *(const bf16x8*)(w + (size_t)(n0 + nb * 16 + l16) * 512 + k0 + quad * 8);
            acc[nb] = MFMA16(af, bf, acc[nb]);
        }
    }
#pragma unroll
    for (int nb = 0; nb < 4; nb++) {
        float bj = b[n0 + nb * 16 + l16];
#pragma unroll
        for (int r = 0; r < 4; r++)
            out[(size_t)(m0 + quad * 4 + r) * 512 + n0 + nb * 16 + l16] =
                acc[nb][r] + bj;    // FP32 store — the round-7 fix
    }
}

extern "C" void kernel_launch(void* const* d_in, const int* in_sizes, int n_in,
                              void* d_out, int out_size, void* d_ws, size_t ws_size,
                              hipStream_t stream) {
    const float* x    = (const float*)d_in[0];
    const float* lat  = (const float*)d_in[1];
    const float* lon  = (const float*)d_in[2];
    const float* wqkv = (const float*)d_in[3];
    const float* bqkv = (const float*)d_in[4];
    const float* wout = (const float*)d_in[5];
    const float* bout = (const float*)d_in[6];
    float* out = (float*)d_out;

    char* ws = (char*)d_ws;
    float* dist        = (float*)ws;                                  // 64 MiB
    double* partials   = (double*)(ws + 67108864);                    // 64 KiB
    float* nis         = (float*)(ws + 67108864 + 65536);             // 64 B
    unsigned short* q  = (unsigned short*)(ws + 67108864 + 65600);
    unsigned short* k  = q  + (size_t)8 * 4096 * 64;   // 4 MiB each
    unsigned short* vt = k  + (size_t)8 * 4096 * 64;
    unsigned short* att = vt + (size_t)8 * 4096 * 64;
    unsigned short* xb  = att + (size_t)4096 * 512;
    unsigned short* wqb = xb  + (size_t)4096 * 512;
    unsigned short* wob = wqb + (size_t)1536 * 512;

    cvt_kernel<<<2048, 256, 0, stream>>>(x, xb, 4096 * 512);
    cvt_kernel<<<768, 256, 0, stream>>>(wqkv, wqb, 1536 * 512);
    cvt_kernel<<<256, 256, 0, stream>>>(wout, wob, 512 * 512);
    dist_kernel<<<4096, 256, 0, stream>>>(lat, lon, dist, partials);
    stats_kernel<<<1, 256, 0, stream>>>(partials, nis);
    qkv_gemm<<<dim3(24, 64), 256, 0, stream>>>(xb, wqb, bqkv, q, k, vt);
    attn_kernel<<<512, 256, 0, stream>>>(q, k, vt, dist, nis, att);
    out_gemm<<<dim3(8, 64), 256, 0, stream>>>(att, wob, bout, out);
}

// Round 8
// 521.818 us; speedup vs baseline: 1.1596x; 1.1596x over previous
//
#include <hip/hip_runtime.h>
#include <hip/hip_bf16.h>

// SphericalAttention on MI355X (gfx950).  ROUND 8: occupancy fix for attn.
// Block = 16 q-rows; 4 waves split KV into 1024-wide quarters; block-level
// (m,l,O) merge in LDS. 2048 blocks -> 32 waves/CU (was 8). pbuf padded
// 64->72 elems (kills the 16-way ds_read_b128 conflict). dist uses HW sin/cos.
// Inputs fp32; output fp32. N=4096, C=512, nh=8, dh=64.

typedef __attribute__((ext_vector_type(8))) short bf16x8;
typedef __attribute__((ext_vector_type(4))) float f32x4;

#define MFMA16(a, b, c) __builtin_amdgcn_mfma_f32_16x16x32_bf16(a, b, c, 0, 0, 0)

__device__ __forceinline__ unsigned short f2b(float f) {
    union { float f; unsigned int i; } v;
    v.f = f;
    unsigned int lsb = (v.i >> 16) & 1u;
    unsigned int r = v.i + 0x7fffu + lsb;   // RNE
    return (unsigned short)(r >> 16);
}

// ---------------------------------------------------------------- fp32 -> bf16
__global__ __launch_bounds__(256) void cvt_kernel(
    const float* __restrict__ in, unsigned short* __restrict__ out, int n) {
    int i = (blockIdx.x * 256 + threadIdx.x) * 4;
    if (i + 3 < n) {
        float4 v = *(const float4*)(in + i);
        ushort4 u;
        u.x = f2b(v.x); u.y = f2b(v.y); u.z = f2b(v.z); u.w = f2b(v.w);
        *(ushort4*)(out + i) = u;
    }
}

// ---------------------------------------------------------------- dist + stats
__global__ __launch_bounds__(256) void dist_kernel(
    const float* __restrict__ lat, const float* __restrict__ lon,
    float* __restrict__ dist, double* __restrict__ partials) {
    __shared__ float sl_i[64], sc_i[64], so_i[64];
    __shared__ float sl_j[64], sc_j[64], so_j[64];
    __shared__ double rs[256], rs2[256];

    int bi = blockIdx.x;
    int i0 = (bi >> 6) << 6;
    int j0 = (bi & 63) << 6;
    int tid = threadIdx.x;

    if (tid < 64) {
        float la = lat[i0 + tid];
        sl_i[tid] = la; sc_i[tid] = __cosf(la); so_i[tid] = lon[i0 + tid];
    } else if (tid < 128) {
        int t = tid - 64;
        float la = lat[j0 + t];
        sl_j[t] = la; sc_j[t] = __cosf(la); so_j[t] = lon[j0 + t];
    }
    __syncthreads();

    double s = 0.0, s2 = 0.0;
    int col = tid & 63;
    float latj = sl_j[col], cj = sc_j[col], lonj = so_j[col];
#pragma unroll
    for (int kk = 0; kk < 16; kk++) {
        int row = (kk << 2) + (tid >> 6);
        float dlat = latj - sl_i[row];
        float dlon = lonj - so_i[row];
        float h1 = __sinf(0.5f * dlat);
        float h2 = __sinf(0.5f * dlon);
        float a = h1 * h1 + sc_i[row] * cj * h2 * h2;
        a = fminf(fmaxf(a, 0.0f), 1.0f);
        float d = 2.0f * asinf(sqrtf(a));
        dist[(size_t)(i0 + row) * 4096 + j0 + col] = d;
        s += (double)d;
        s2 += (double)d * (double)d;
    }
    rs[tid] = s; rs2[tid] = s2;
    __syncthreads();
    for (int off = 128; off > 0; off >>= 1) {
        if (tid < off) { rs[tid] += rs[tid + off]; rs2[tid] += rs2[tid + off]; }
        __syncthreads();
    }
    if (tid == 0) {
        partials[2 * bi] = rs[0];
        partials[2 * bi + 1] = rs2[0];
    }
}

__global__ __launch_bounds__(256) void stats_kernel(
    const double* __restrict__ partials, float* __restrict__ neg_inv_std) {
    __shared__ double rs[256], rs2[256];
    int tid = threadIdx.x;
    double s = 0.0, s2 = 0.0;
    for (int i = tid; i < 4096; i += 256) {
        s += partials[2 * i];
        s2 += partials[2 * i + 1];
    }
    rs[tid] = s; rs2[tid] = s2;
    __syncthreads();
    for (int off = 128; off > 0; off >>= 1) {
        if (tid < off) { rs[tid] += rs[tid + off]; rs2[tid] += rs2[tid + off]; }
        __syncthreads();
    }
    if (tid == 0) {
        double n = 16777216.0;
        double mean = rs[0] / n;
        double var = (rs2[0] - n * mean * mean) / (n - 1.0);  // ddof=1
        *neg_inv_std = (float)(-1.0 / sqrt(var));
    }
}

// ---------------------------------------------------------------- QKV GEMM
__global__ __launch_bounds__(256) void qkv_gemm(
    const unsigned short* __restrict__ x, const unsigned short* __restrict__ w,
    const float* __restrict__ b,
    unsigned short* __restrict__ q, unsigned short* __restrict__ k,
    unsigned short* __restrict__ vt) {
    int lane = threadIdx.x & 63, wave = threadIdx.x >> 6;
    int l16 = lane & 15, quad = lane >> 4;
    int m0 = blockIdx.y * 64 + wave * 16;
    int n0 = blockIdx.x * 64;

    const unsigned short* arow = x + (size_t)(m0 + l16) * 512 + quad * 8;
    f32x4 acc[4];
#pragma unroll
    for (int nb = 0; nb < 4; nb++) acc[nb] = (f32x4){0.f, 0.f, 0.f, 0.f};

    for (int k0 = 0; k0 < 512; k0 += 32) {
        bf16x8 af = *(const bf16x8*)(arow + k0);
#pragma unroll
        for (int nb = 0; nb < 4; nb++) {
            bf16x8 bf = *(const bf16x8*)(w + (size_t)(n0 + nb * 16 + l16) * 512 + k0 + quad * 8);
            acc[nb] = MFMA16(af, bf, acc[nb]);
        }
    }
#pragma unroll
    for (int nb = 0; nb < 4; nb++) {
        int j = n0 + nb * 16 + l16;
        float bj = b[j];
        int s = j >> 9;         // 0=q 1=k 2=v
        int rem = j & 511;
        int h = rem >> 6, d = rem & 63;
#pragma unroll
        for (int r = 0; r < 4; r++) {
            int n = m0 + quad * 4 + r;
            unsigned short u = f2b(acc[nb][r] + bj);
            if (s == 0)      q[((size_t)h * 4096 + n) * 64 + d] = u;
            else if (s == 1) k[((size_t)h * 4096 + n) * 64 + d] = u;
            else             vt[((size_t)h * 64 + d) * 4096 + n] = u;
        }
    }
}

// ---------------------------------------------------------------- flash attention
// Block = (head, 16 q-rows). 4 waves split KV into 1024-wide quarters;
// block-level online-softmax merge through LDS at the end.
__global__ __launch_bounds__(256, 8) void attn_kernel(
    const unsigned short* __restrict__ q, const unsigned short* __restrict__ k,
    const unsigned short* __restrict__ vt, const float* __restrict__ dist,
    const float* __restrict__ nis_p, unsigned short* __restrict__ att) {
    // union: per-wave pbuf [4][16*72]u16 (9216 B) then combine bufs (16896 B)
    __shared__ char smem[16896];
    int lane = threadIdx.x & 63, wave = threadIdx.x >> 6;
    int l16 = lane & 15, quad = lane >> 4;
    int h = blockIdx.x >> 8;
    int q0 = (blockIdx.x & 255) * 16;
    int kvbase = wave * 1024;
    float nis = *nis_p;
    const float scale = 0.125f;

    unsigned short* pb = (unsigned short*)smem + wave * 1152;   // 16 x 72

    const unsigned short* qbase = q + ((size_t)h * 4096 + q0 + l16) * 64 + quad * 8;
    bf16x8 qf0 = *(const bf16x8*)(qbase);
    bf16x8 qf1 = *(const bf16x8*)(qbase + 32);

    f32x4 o[4];
    float m[4], l[4];
#pragma unroll
    for (int r = 0; r < 4; r++) {
        m[r] = -1e30f; l[r] = 0.f;
        o[0][r] = 0.f; o[1][r] = 0.f; o[2][r] = 0.f; o[3][r] = 0.f;
    }

    for (int kv0 = kvbase; kv0 < kvbase + 1024; kv0 += 64) {
        f32x4 s[4];
#pragma unroll
        for (int cb = 0; cb < 4; cb++) {
            const unsigned short* kbase =
                k + ((size_t)h * 4096 + kv0 + cb * 16 + l16) * 64 + quad * 8;
            bf16x8 kf0 = *(const bf16x8*)(kbase);
            bf16x8 kf1 = *(const bf16x8*)(kbase + 32);
            f32x4 z = (f32x4){0.f, 0.f, 0.f, 0.f};
            z = MFMA16(qf0, kf0, z);
            z = MFMA16(qf1, kf1, z);
            s[cb] = z;
        }
#pragma unroll
        for (int r = 0; r < 4; r++) {
            const float* drow = dist + (size_t)(q0 + quad * 4 + r) * 4096 + kv0 + l16;
#pragma unroll
            for (int cb = 0; cb < 4; cb++)
                s[cb][r] = s[cb][r] * scale + drow[cb * 16] * nis;
        }
        float mt[4];
#pragma unroll
        for (int r = 0; r < 4; r++) {
            float v = fmaxf(fmaxf(s[0][r], s[1][r]), fmaxf(s[2][r], s[3][r]));
#pragma unroll
            for (int off = 1; off < 16; off <<= 1)
                v = fmaxf(v, __shfl_xor(v, off, 64));
            mt[r] = v;
        }
        float al[4];
#pragma unroll
        for (int r = 0; r < 4; r++) {
            float mn = fmaxf(m[r], mt[r]);
            al[r] = __expf(m[r] - mn);
            m[r] = mn;
        }
        float rsum[4] = {0.f, 0.f, 0.f, 0.f};
#pragma unroll
        for (int cb = 0; cb < 4; cb++)
#pragma unroll
            for (int r = 0; r < 4; r++) {
                float p = __expf(s[cb][r] - m[r]);
                s[cb][r] = p;
                rsum[r] += p;
            }
#pragma unroll
        for (int r = 0; r < 4; r++) {
#pragma unroll
            for (int off = 1; off < 16; off <<= 1)
                rsum[r] += __shfl_xor(rsum[r], off, 64);
            l[r] = l[r] * al[r] + rsum[r];
            o[0][r] *= al[r]; o[1][r] *= al[r]; o[2][r] *= al[r]; o[3][r] *= al[r];
        }
        // P (C-layout) -> LDS -> A-operand layout; stride 72 kills conflicts
#pragma unroll
        for (int cb = 0; cb < 4; cb++)
#pragma unroll
            for (int r = 0; r < 4; r++)
                pb[(quad * 4 + r) * 72 + cb * 16 + l16] = f2b(s[cb][r]);
        asm volatile("s_waitcnt lgkmcnt(0)" ::: "memory");
        bf16x8 pf0 = *(const bf16x8*)(pb + l16 * 72 + quad * 8);
        bf16x8 pf1 = *(const bf16x8*)(pb + l16 * 72 + 32 + quad * 8);
#pragma unroll
        for (int db = 0; db < 4; db++) {
            const unsigned short* vbase =
                vt + ((size_t)h * 64 + db * 16 + l16) * 4096 + kv0 + quad * 8;
            bf16x8 vf0 = *(const bf16x8*)(vbase);
            bf16x8 vf1 = *(const bf16x8*)(vbase + 32);
            o[db] = MFMA16(pf0, vf0, o[db]);
            o[db] = MFMA16(pf1, vf1, o[db]);
        }
    }

    // -------- block-level merge of 4 KV-chunk partials
    __syncthreads();                       // all waves done with pbuf
    float* obuf = (float*)smem;            // [4 chunk][16 row][64 d]
    float* mlbuf = (float*)(smem + 16384); // [4 chunk][16 row][2]
#pragma unroll
    for (int db = 0; db < 4; db++)
#pragma unroll
        for (int r = 0; r < 4; r++)
            obuf[(wave * 16 + quad * 4 + r) * 64 + db * 16 + l16] = o[db][r];
    if (l16 == 0)
#pragma unroll
        for (int r = 0; r < 4; r++) {
            mlbuf[(wave * 16 + quad * 4 + r) * 2 + 0] = m[r];
            mlbuf[(wave * 16 + quad * 4 + r) * 2 + 1] = l[r];
        }
    __syncthreads();

    int d = threadIdx.x & 63;
#pragma unroll
    for (int i = 0; i < 4; i++) {
        int row = (threadIdx.x >> 6) * 4 + i;
        float m0c = mlbuf[(0 * 16 + row) * 2], m1c = mlbuf[(1 * 16 + row) * 2];
        float m2c = mlbuf[(2 * 16 + row) * 2], m3c = mlbuf[(3 * 16 + row) * 2];
        float M = fmaxf(fmaxf(m0c, m1c), fmaxf(m2c, m3c));
        float e0 = __expf(m0c - M), e1 = __expf(m1c - M);
        float e2 = __expf(m2c - M), e3 = __expf(m3c - M);
        float L = mlbuf[(0 * 16 + row) * 2 + 1] * e0 + mlbuf[(1 * 16 + row) * 2 + 1] * e1
                + mlbuf[(2 * 16 + row) * 2 + 1] * e2 + mlbuf[(3 * 16 + row) * 2 + 1] * e3;
        float O = obuf[(0 * 16 + row) * 64 + d] * e0 + obuf[(1 * 16 + row) * 64 + d] * e1
                + obuf[(2 * 16 + row) * 64 + d] * e2 + obuf[(3 * 16 + row) * 64 + d] * e3;
        att[(size_t)(q0 + row) * 512 + h * 64 + d] = f2b(O / L);
    }
}

// ---------------------------------------------------------------- output GEMM (fp32 store)
__global__ __launch_bounds__(256) void out_gemm(
    const unsigned short* __restrict__ att, const unsigned short* __restrict__ w,
    const float* __restrict__ b, float* __restrict__ out) {
    int lane = threadIdx.x & 63, wave = threadIdx.x >> 6;
    int l16 = lane & 15, quad = lane >> 4;
    int m0 = blockIdx.y * 64 + wave * 16;
    int n0 = blockIdx.x * 64;

    const unsigned short* arow = att + (size_t)(m0 + l16) * 512 + quad * 8;
    f32x4 acc[4];
#pragma unroll
    for (int nb = 0; nb < 4; nb++) acc[nb] = (f32x4){0.f, 0.f, 0.f, 0.f};

    for (int k0 = 0; k0 < 512; k0 += 32) {
        bf16x8 af = *(const bf16x8*)(arow + k0);
#pragma unroll
        for (int nb = 0; nb < 4; nb++) {
            bf16x8 bf = *(const bf16x8*)(w + (size_t)(n0 + nb * 16 + l16) * 512 + k0 + quad * 8);
            acc[nb] = MFMA16(af, bf, acc[nb]);
        }
    }
#pragma unroll
    for (int nb = 0; nb < 4; nb++) {
        float bj = b[n0 + nb * 16 + l16];
#pragma unroll
        for (int r = 0; r < 4; r++)
            out[(size_t)(m0 + quad * 4 + r) * 512 + n0 + nb * 16 + l16] =
                acc[nb][r] + bj;
    }
}

extern "C" void kernel_launch(void* const* d_in, const int* in_sizes, int n_in,
                              void* d_out, int out_size, void* d_ws, size_t ws_size,
                              hipStream_t stream) {
    const float* x    = (const float*)d_in[0];
    const float* lat  = (const float*)d_in[1];
    const float* lon  = (const float*)d_in[2];
    const float* wqkv = (const float*)d_in[3];
    const float* bqkv = (const float*)d_in[4];
    const float* wout = (const float*)d_in[5];
    const float* bout = (const float*)d_in[6];
    float* out = (float*)d_out;

    char* ws = (char*)d_ws;
    float* dist        = (float*)ws;                                  // 64 MiB
    double* partials   = (double*)(ws + 67108864);                    // 64 KiB
    float* nis         = (float*)(ws + 67108864 + 65536);             // 64 B
    unsigned short* q  = (unsigned short*)(ws + 67108864 + 65600);
    unsigned short* k  = q  + (size_t)8 * 4096 * 64;   // 4 MiB each
    unsigned short* vt = k  + (size_t)8 * 4096 * 64;
    unsigned short* att = vt + (size_t)8 * 4096 * 64;
    unsigned short* xb  = att + (size_t)4096 * 512;
    unsigned short* wqb = xb  + (size_t)4096 * 512;
    unsigned short* wob = wqb + (size_t)1536 * 512;

    cvt_kernel<<<2048, 256, 0, stream>>>(x, xb, 4096 * 512);
    cvt_kernel<<<768, 256, 0, stream>>>(wqkv, wqb, 1536 * 512);
    cvt_kernel<<<256, 256, 0, stream>>>(wout, wob, 512 * 512);
    dist_kernel<<<4096, 256, 0, stream>>>(lat, lon, dist, partials);
    stats_kernel<<<1, 256, 0, stream>>>(partials, nis);
    qkv_gemm<<<dim3(24, 64), 256, 0, stream>>>(xb, wqb, bqkv, q, k, vt);
    attn_kernel<<<2048, 256, 0, stream>>>(q, k, vt, dist, nis, att);
    out_gemm<<<dim3(8, 64), 256, 0, stream>>>(att, wob, bout, out);
}

// Round 9
// 482.737 us; speedup vs baseline: 1.2535x; 1.0810x over previous
//
#include <hip/hip_runtime.h>
#include <hip/hip_bf16.h>

// SphericalAttention on MI355X (gfx950).  ROUND 9: revert the forced
// __launch_bounds__(256,8) on attn (it capped VGPR at 32 -> massive scratch
// spills: WRITE_SIZE 234 MB vs 4 MB actual output). Plain (256) gives the
// R7-proven 64-VGPR spill-free allocation; KV-split + block merge + padded
// pbuf + fast sin/cos all retained.
// Inputs fp32; output fp32. N=4096, C=512, nh=8, dh=64.

typedef __attribute__((ext_vector_type(8))) short bf16x8;
typedef __attribute__((ext_vector_type(4))) float f32x4;

#define MFMA16(a, b, c) __builtin_amdgcn_mfma_f32_16x16x32_bf16(a, b, c, 0, 0, 0)

__device__ __forceinline__ unsigned short f2b(float f) {
    union { float f; unsigned int i; } v;
    v.f = f;
    unsigned int lsb = (v.i >> 16) & 1u;
    unsigned int r = v.i + 0x7fffu + lsb;   // RNE
    return (unsigned short)(r >> 16);
}

// ---------------------------------------------------------------- fp32 -> bf16
__global__ __launch_bounds__(256) void cvt_kernel(
    const float* __restrict__ in, unsigned short* __restrict__ out, int n) {
    int i = (blockIdx.x * 256 + threadIdx.x) * 4;
    if (i + 3 < n) {
        float4 v = *(const float4*)(in + i);
        ushort4 u;
        u.x = f2b(v.x); u.y = f2b(v.y); u.z = f2b(v.z); u.w = f2b(v.w);
        *(ushort4*)(out + i) = u;
    }
}

// ---------------------------------------------------------------- dist + stats
__global__ __launch_bounds__(256) void dist_kernel(
    const float* __restrict__ lat, const float* __restrict__ lon,
    float* __restrict__ dist, double* __restrict__ partials) {
    __shared__ float sl_i[64], sc_i[64], so_i[64];
    __shared__ float sl_j[64], sc_j[64], so_j[64];
    __shared__ double rs[256], rs2[256];

    int bi = blockIdx.x;
    int i0 = (bi >> 6) << 6;
    int j0 = (bi & 63) << 6;
    int tid = threadIdx.x;

    if (tid < 64) {
        float la = lat[i0 + tid];
        sl_i[tid] = la; sc_i[tid] = __cosf(la); so_i[tid] = lon[i0 + tid];
    } else if (tid < 128) {
        int t = tid - 64;
        float la = lat[j0 + t];
        sl_j[t] = la; sc_j[t] = __cosf(la); so_j[t] = lon[j0 + t];
    }
    __syncthreads();

    double s = 0.0, s2 = 0.0;
    int col = tid & 63;
    float latj = sl_j[col], cj = sc_j[col], lonj = so_j[col];
#pragma unroll
    for (int kk = 0; kk < 16; kk++) {
        int row = (kk << 2) + (tid >> 6);
        float dlat = latj - sl_i[row];
        float dlon = lonj - so_i[row];
        float h1 = __sinf(0.5f * dlat);
        float h2 = __sinf(0.5f * dlon);
        float a = h1 * h1 + sc_i[row] * cj * h2 * h2;
        a = fminf(fmaxf(a, 0.0f), 1.0f);
        float d = 2.0f * asinf(sqrtf(a));
        dist[(size_t)(i0 + row) * 4096 + j0 + col] = d;
        s += (double)d;
        s2 += (double)d * (double)d;
    }
    rs[tid] = s; rs2[tid] = s2;
    __syncthreads();
    for (int off = 128; off > 0; off >>= 1) {
        if (tid < off) { rs[tid] += rs[tid + off]; rs2[tid] += rs2[tid + off]; }
        __syncthreads();
    }
    if (tid == 0) {
        partials[2 * bi] = rs[0];
        partials[2 * bi + 1] = rs2[0];
    }
}

__global__ __launch_bounds__(256) void stats_kernel(
    const double* __restrict__ partials, float* __restrict__ neg_inv_std) {
    __shared__ double rs[256], rs2[256];
    int tid = threadIdx.x;
    double s = 0.0, s2 = 0.0;
    for (int i = tid; i < 4096; i += 256) {
        s += partials[2 * i];
        s2 += partials[2 * i + 1];
    }
    rs[tid] = s; rs2[tid] = s2;
    __syncthreads();
    for (int off = 128; off > 0; off >>= 1) {
        if (tid < off) { rs[tid] += rs[tid + off]; rs2[tid] += rs2[tid + off]; }
        __syncthreads();
    }
    if (tid == 0) {
        double n = 16777216.0;
        double mean = rs[0] / n;
        double var = (rs2[0] - n * mean * mean) / (n - 1.0);  // ddof=1
        *neg_inv_std = (float)(-1.0 / sqrt(var));
    }
}

// ---------------------------------------------------------------- QKV GEMM
__global__ __launch_bounds__(256) void qkv_gemm(
    const unsigned short* __restrict__ x, const unsigned short* __restrict__ w,
    const float* __restrict__ b,
    unsigned short* __restrict__ q, unsigned short* __restrict__ k,
    unsigned short* __restrict__ vt) {
    int lane = threadIdx.x & 63, wave = threadIdx.x >> 6;
    int l16 = lane & 15, quad = lane >> 4;
    int m0 = blockIdx.y * 64 + wave * 16;
    int n0 = blockIdx.x * 64;

    const unsigned short* arow = x + (size_t)(m0 + l16) * 512 + quad * 8;
    f32x4 acc[4];
#pragma unroll
    for (int nb = 0; nb < 4; nb++) acc[nb] = (f32x4){0.f, 0.f, 0.f, 0.f};

    for (int k0 = 0; k0 < 512; k0 += 32) {
        bf16x8 af = *(const bf16x8*)(arow + k0);
#pragma unroll
        for (int nb = 0; nb < 4; nb++) {
            bf16x8 bf = *(const bf16x8*)(w + (size_t)(n0 + nb * 16 + l16) * 512 + k0 + quad * 8);
            acc[nb] = MFMA16(af, bf, acc[nb]);
        }
    }
#pragma unroll
    for (int nb = 0; nb < 4; nb++) {
        int j = n0 + nb * 16 + l16;
        float bj = b[j];
        int s = j >> 9;         // 0=q 1=k 2=v
        int rem = j & 511;
        int h = rem >> 6, d = rem & 63;
#pragma unroll
        for (int r = 0; r < 4; r++) {
            int n = m0 + quad * 4 + r;
            unsigned short u = f2b(acc[nb][r] + bj);
            if (s == 0)      q[((size_t)h * 4096 + n) * 64 + d] = u;
            else if (s == 1) k[((size_t)h * 4096 + n) * 64 + d] = u;
            else             vt[((size_t)h * 64 + d) * 4096 + n] = u;
        }
    }
}

// ---------------------------------------------------------------- flash attention
// Block = (head, 16 q-rows). 4 waves split KV into 1024-wide quarters;
// block-level online-softmax merge through LDS at the end.
// Plain launch_bounds: R7 proved 64-VGPR spill-free for this loop body.
__global__ __launch_bounds__(256) void attn_kernel(
    const unsigned short* __restrict__ q, const unsigned short* __restrict__ k,
    const unsigned short* __restrict__ vt, const float* __restrict__ dist,
    const float* __restrict__ nis_p, unsigned short* __restrict__ att) {
    // union: per-wave pbuf [4][16*72]u16 (9216 B) then combine bufs (16896 B)
    __shared__ char smem[16896];
    int lane = threadIdx.x & 63, wave = threadIdx.x >> 6;
    int l16 = lane & 15, quad = lane >> 4;
    int h = blockIdx.x >> 8;
    int q0 = (blockIdx.x & 255) * 16;
    int kvbase = wave * 1024;
    float nis = *nis_p;
    const float scale = 0.125f;

    unsigned short* pb = (unsigned short*)smem + wave * 1152;   // 16 x 72

    const unsigned short* qbase = q + ((size_t)h * 4096 + q0 + l16) * 64 + quad * 8;
    bf16x8 qf0 = *(const bf16x8*)(qbase);
    bf16x8 qf1 = *(const bf16x8*)(qbase + 32);

    f32x4 o[4];
    float m[4], l[4];
#pragma unroll
    for (int r = 0; r < 4; r++) {
        m[r] = -1e30f; l[r] = 0.f;
        o[0][r] = 0.f; o[1][r] = 0.f; o[2][r] = 0.f; o[3][r] = 0.f;
    }

    for (int kv0 = kvbase; kv0 < kvbase + 1024; kv0 += 64) {
        f32x4 s[4];
#pragma unroll
        for (int cb = 0; cb < 4; cb++) {
            const unsigned short* kbase =
                k + ((size_t)h * 4096 + kv0 + cb * 16 + l16) * 64 + quad * 8;
            bf16x8 kf0 = *(const bf16x8*)(kbase);
            bf16x8 kf1 = *(const bf16x8*)(kbase + 32);
            f32x4 z = (f32x4){0.f, 0.f, 0.f, 0.f};
            z = MFMA16(qf0, kf0, z);
            z = MFMA16(qf1, kf1, z);
            s[cb] = z;
        }
#pragma unroll
        for (int r = 0; r < 4; r++) {
            const float* drow = dist + (size_t)(q0 + quad * 4 + r) * 4096 + kv0 + l16;
#pragma unroll
            for (int cb = 0; cb < 4; cb++)
                s[cb][r] = s[cb][r] * scale + drow[cb * 16] * nis;
        }
        float mt[4];
#pragma unroll
        for (int r = 0; r < 4; r++) {
            float v = fmaxf(fmaxf(s[0][r], s[1][r]), fmaxf(s[2][r], s[3][r]));
#pragma unroll
            for (int off = 1; off < 16; off <<= 1)
                v = fmaxf(v, __shfl_xor(v, off, 64));
            mt[r] = v;
        }
        float al[4];
#pragma unroll
        for (int r = 0; r < 4; r++) {
            float mn = fmaxf(m[r], mt[r]);
            al[r] = __expf(m[r] - mn);
            m[r] = mn;
        }
        float rsum[4] = {0.f, 0.f, 0.f, 0.f};
#pragma unroll
        for (int cb = 0; cb < 4; cb++)
#pragma unroll
            for (int r = 0; r < 4; r++) {
                float p = __expf(s[cb][r] - m[r]);
                s[cb][r] = p;
                rsum[r] += p;
            }
#pragma unroll
        for (int r = 0; r < 4; r++) {
#pragma unroll
            for (int off = 1; off < 16; off <<= 1)
                rsum[r] += __shfl_xor(rsum[r], off, 64);
            l[r] = l[r] * al[r] + rsum[r];
            o[0][r] *= al[r]; o[1][r] *= al[r]; o[2][r] *= al[r]; o[3][r] *= al[r];
        }
        // P (C-layout) -> LDS -> A-operand layout; stride 72 kills conflicts
#pragma unroll
        for (int cb = 0; cb < 4; cb++)
#pragma unroll
            for (int r = 0; r < 4; r++)
                pb[(quad * 4 + r) * 72 + cb * 16 + l16] = f2b(s[cb][r]);
        asm volatile("s_waitcnt lgkmcnt(0)" ::: "memory");
        bf16x8 pf0 = *(const bf16x8*)(pb + l16 * 72 + quad * 8);
        bf16x8 pf1 = *(const bf16x8*)(pb + l16 * 72 + 32 + quad * 8);
#pragma unroll
        for (int db = 0; db < 4; db++) {
            const unsigned short* vbase =
                vt + ((size_t)h * 64 + db * 16 + l16) * 4096 + kv0 + quad * 8;
            bf16x8 vf0 = *(const bf16x8*)(vbase);
            bf16x8 vf1 = *(const bf16x8*)(vbase + 32);
            o[db] = MFMA16(pf0, vf0, o[db]);
            o[db] = MFMA16(pf1, vf1, o[db]);
        }
    }

    // -------- block-level merge of 4 KV-chunk partials
    __syncthreads();                       // all waves done with pbuf
    float* obuf = (float*)smem;            // [4 chunk][16 row][64 d]
    float* mlbuf = (float*)(smem + 16384); // [4 chunk][16 row][2]
#pragma unroll
    for (int db = 0; db < 4; db++)
#pragma unroll
        for (int r = 0; r < 4; r++)
            obuf[(wave * 16 + quad * 4 + r) * 64 + db * 16 + l16] = o[db][r];
    if (l16 == 0)
#pragma unroll
        for (int r = 0; r < 4; r++) {
            mlbuf[(wave * 16 + quad * 4 + r) * 2 + 0] = m[r];
            mlbuf[(wave * 16 + quad * 4 + r) * 2 + 1] = l[r];
        }
    __syncthreads();

    int d = threadIdx.x & 63;
#pragma unroll
    for (int i = 0; i < 4; i++) {
        int row = (threadIdx.x >> 6) * 4 + i;
        float m0c = mlbuf[(0 * 16 + row) * 2], m1c = mlbuf[(1 * 16 + row) * 2];
        float m2c = mlbuf[(2 * 16 + row) * 2], m3c = mlbuf[(3 * 16 + row) * 2];
        float M = fmaxf(fmaxf(m0c, m1c), fmaxf(m2c, m3c));
        float e0 = __expf(m0c - M), e1 = __expf(m1c - M);
        float e2 = __expf(m2c - M), e3 = __expf(m3c - M);
        float L = mlbuf[(0 * 16 + row) * 2 + 1] * e0 + mlbuf[(1 * 16 + row) * 2 + 1] * e1
                + mlbuf[(2 * 16 + row) * 2 + 1] * e2 + mlbuf[(3 * 16 + row) * 2 + 1] * e3;
        float O = obuf[(0 * 16 + row) * 64 + d] * e0 + obuf[(1 * 16 + row) * 64 + d] * e1
                + obuf[(2 * 16 + row) * 64 + d] * e2 + obuf[(3 * 16 + row) * 64 + d] * e3;
        att[(size_t)(q0 + row) * 512 + h * 64 + d] = f2b(O / L);
    }
}

// ---------------------------------------------------------------- output GEMM (fp32 store)
__global__ __launch_bounds__(256) void out_gemm(
    const unsigned short* __restrict__ att, const unsigned short* __restrict__ w,
    const float* __restrict__ b, float* __restrict__ out) {
    int lane = threadIdx.x & 63, wave = threadIdx.x >> 6;
    int l16 = lane & 15, quad = lane >> 4;
    int m0 = blockIdx.y * 64 + wave * 16;
    int n0 = blockIdx.x * 64;

    const unsigned short* arow = att + (size_t)(m0 + l16) * 512 + quad * 8;
    f32x4 acc[4];
#pragma unroll
    for (int nb = 0; nb < 4; nb++) acc[nb] = (f32x4){0.f, 0.f, 0.f, 0.f};

    for (int k0 = 0; k0 < 512; k0 += 32) {
        bf16x8 af = *(const bf16x8*)(arow + k0);
#pragma unroll
        for (int nb = 0; nb < 4; nb++) {
            bf16x8 bf = *(const bf16x8*)(w + (size_t)(n0 + nb * 16 + l16) * 512 + k0 + quad * 8);
            acc[nb] = MFMA16(af, bf, acc[nb]);
        }
    }
#pragma unroll
    for (int nb = 0; nb < 4; nb++) {
        float bj = b[n0 + nb * 16 + l16];
#pragma unroll
        for (int r = 0; r < 4; r++)
            out[(size_t)(m0 + quad * 4 + r) * 512 + n0 + nb * 16 + l16] =
                acc[nb][r] + bj;
    }
}

extern "C" void kernel_launch(void* const* d_in, const int* in_sizes, int n_in,
                              void* d_out, int out_size, void* d_ws, size_t ws_size,
                              hipStream_t stream) {
    const float* x    = (const float*)d_in[0];
    const float* lat  = (const float*)d_in[1];
    const float* lon  = (const float*)d_in[2];
    const float* wqkv = (const float*)d_in[3];
    const float* bqkv = (const float*)d_in[4];
    const float* wout = (const float*)d_in[5];
    const float* bout = (const float*)d_in[6];
    float* out = (float*)d_out;

    char* ws = (char*)d_ws;
    float* dist        = (float*)ws;                                  // 64 MiB
    double* partials   = (double*)(ws + 67108864);                    // 64 KiB
    float* nis         = (float*)(ws + 67108864 + 65536);             // 64 B
    unsigned short* q  = (unsigned short*)(ws + 67108864 + 65600);
    unsigned short* k  = q  + (size_t)8 * 4096 * 64;   // 4 MiB each
    unsigned short* vt = k  + (size_t)8 * 4096 * 64;
    unsigned short* att = vt + (size_t)8 * 4096 * 64;
    unsigned short* xb  = att + (size_t)4096 * 512;
    unsigned short* wqb = xb  + (size_t)4096 * 512;
    unsigned short* wob = wqb + (size_t)1536 * 512;

    cvt_kernel<<<2048, 256, 0, stream>>>(x, xb, 4096 * 512);
    cvt_kernel<<<768, 256, 0, stream>>>(wqkv, wqb, 1536 * 512);
    cvt_kernel<<<256, 256, 0, stream>>>(wout, wob, 512 * 512);
    dist_kernel<<<4096, 256, 0, stream>>>(lat, lon, dist, partials);
    stats_kernel<<<1, 256, 0, stream>>>(partials, nis);
    qkv_gemm<<<dim3(24, 64), 256, 0, stream>>>(xb, wqb, bqkv, q, k, vt);
    attn_kernel<<<2048, 256, 0, stream>>>(q, k, vt, dist, nis, att);
    out_gemm<<<dim3(8, 64), 256, 0, stream>>>(att, wob, bout, out);
}

// Round 13
// 481.616 us; speedup vs baseline: 1.2564x; 1.0023x over previous
//
#include <hip/hip_runtime.h>
#include <hip/hip_bf16.h>

// SphericalAttention on MI355X (gfx950).  ROUND 13: R9 (green, 483us) + one
// iron-clad change: lambda-deferral in attn. The row-sum shuffle chain (16
// shuffles/iter) is replaced by per-lane partials rescaled by the row-uniform
// al[r] and reduced ONCE post-loop (exact reassociation of R9's linear sum).
// Online max-tracking kept verbatim — the max-free variant NaN'd in R10-R12
// for reasons unexplained (R11 proved it's not the exp path; mechanism open).
// Inputs fp32; output fp32. N=4096, C=512, nh=8, dh=64.

typedef __attribute__((ext_vector_type(8))) short bf16x8;
typedef __attribute__((ext_vector_type(4))) float f32x4;

#define MFMA16(a, b, c) __builtin_amdgcn_mfma_f32_16x16x32_bf16(a, b, c, 0, 0, 0)

__device__ __forceinline__ unsigned short f2b(float f) {
    union { float f; unsigned int i; } v;
    v.f = f;
    unsigned int lsb = (v.i >> 16) & 1u;
    unsigned int r = v.i + 0x7fffu + lsb;   // RNE
    return (unsigned short)(r >> 16);
}

// ---------------------------------------------------------------- fp32 -> bf16
__global__ __launch_bounds__(256) void cvt_kernel(
    const float* __restrict__ in, unsigned short* __restrict__ out, int n) {
    int i = (blockIdx.x * 256 + threadIdx.x) * 4;
    if (i + 3 < n) {
        float4 v = *(const float4*)(in + i);
        ushort4 u;
        u.x = f2b(v.x); u.y = f2b(v.y); u.z = f2b(v.z); u.w = f2b(v.w);
        *(ushort4*)(out + i) = u;
    }
}

// ---------------------------------------------------------------- dist + stats
__global__ __launch_bounds__(256) void dist_kernel(
    const float* __restrict__ lat, const float* __restrict__ lon,
    float* __restrict__ dist, double* __restrict__ partials) {
    __shared__ float sl_i[64], sc_i[64], so_i[64];
    __shared__ float sl_j[64], sc_j[64], so_j[64];
    __shared__ double rs[256], rs2[256];

    int bi = blockIdx.x;
    int i0 = (bi >> 6) << 6;
    int j0 = (bi & 63) << 6;
    int tid = threadIdx.x;

    if (tid < 64) {
        float la = lat[i0 + tid];
        sl_i[tid] = la; sc_i[tid] = __cosf(la); so_i[tid] = lon[i0 + tid];
    } else if (tid < 128) {
        int t = tid - 64;
        float la = lat[j0 + t];
        sl_j[t] = la; sc_j[t] = __cosf(la); so_j[t] = lon[j0 + t];
    }
    __syncthreads();

    double s = 0.0, s2 = 0.0;
    int col = tid & 63;
    float latj = sl_j[col], cj = sc_j[col], lonj = so_j[col];
#pragma unroll
    for (int kk = 0; kk < 16; kk++) {
        int row = (kk << 2) + (tid >> 6);
        float dlat = latj - sl_i[row];
        float dlon = lonj - so_i[row];
        float h1 = __sinf(0.5f * dlat);
        float h2 = __sinf(0.5f * dlon);
        float a = h1 * h1 + sc_i[row] * cj * h2 * h2;
        a = fminf(fmaxf(a, 0.0f), 1.0f);
        float d = 2.0f * asinf(sqrtf(a));
        dist[(size_t)(i0 + row) * 4096 + j0 + col] = d;
        s += (double)d;
        s2 += (double)d * (double)d;
    }
    rs[tid] = s; rs2[tid] = s2;
    __syncthreads();
    for (int off = 128; off > 0; off >>= 1) {
        if (tid < off) { rs[tid] += rs[tid + off]; rs2[tid] += rs2[tid + off]; }
        __syncthreads();
    }
    if (tid == 0) {
        partials[2 * bi] = rs[0];
        partials[2 * bi + 1] = rs2[0];
    }
}

__global__ __launch_bounds__(256) void stats_kernel(
    const double* __restrict__ partials, float* __restrict__ neg_inv_std) {
    __shared__ double rs[256], rs2[256];
    int tid = threadIdx.x;
    double s = 0.0, s2 = 0.0;
    for (int i = tid; i < 4096; i += 256) {
        s += partials[2 * i];
        s2 += partials[2 * i + 1];
    }
    rs[tid] = s; rs2[tid] = s2;
    __syncthreads();
    for (int off = 128; off > 0; off >>= 1) {
        if (tid < off) { rs[tid] += rs[tid + off]; rs2[tid] += rs2[tid + off]; }
        __syncthreads();
    }
    if (tid == 0) {
        double n = 16777216.0;
        double mean = rs[0] / n;
        double var = (rs2[0] - n * mean * mean) / (n - 1.0);  // ddof=1
        *neg_inv_std = (float)(-1.0 / sqrt(var));
    }
}

// ---------------------------------------------------------------- QKV GEMM
__global__ __launch_bounds__(256) void qkv_gemm(
    const unsigned short* __restrict__ x, const unsigned short* __restrict__ w,
    const float* __restrict__ b,
    unsigned short* __restrict__ q, unsigned short* __restrict__ k,
    unsigned short* __restrict__ vt) {
    int lane = threadIdx.x & 63, wave = threadIdx.x >> 6;
    int l16 = lane & 15, quad = lane >> 4;
    int m0 = blockIdx.y * 64 + wave * 16;
    int n0 = blockIdx.x * 64;

    const unsigned short* arow = x + (size_t)(m0 + l16) * 512 + quad * 8;
    f32x4 acc[4];
#pragma unroll
    for (int nb = 0; nb < 4; nb++) acc[nb] = (f32x4){0.f, 0.f, 0.f, 0.f};

    for (int k0 = 0; k0 < 512; k0 += 32) {
        bf16x8 af = *(const bf16x8*)(arow + k0);
#pragma unroll
        for (int nb = 0; nb < 4; nb++) {
            bf16x8 bf = *(const bf16x8*)(w + (size_t)(n0 + nb * 16 + l16) * 512 + k0 + quad * 8);
            acc[nb] = MFMA16(af, bf, acc[nb]);
        }
    }
#pragma unroll
    for (int nb = 0; nb < 4; nb++) {
        int j = n0 + nb * 16 + l16;
        float bj = b[j];
        int s = j >> 9;         // 0=q 1=k 2=v
        int rem = j & 511;
        int h = rem >> 6, d = rem & 63;
#pragma unroll
        for (int r = 0; r < 4; r++) {
            int n = m0 + quad * 4 + r;
            unsigned short u = f2b(acc[nb][r] + bj);
            if (s == 0)      q[((size_t)h * 4096 + n) * 64 + d] = u;
            else if (s == 1) k[((size_t)h * 4096 + n) * 64 + d] = u;
            else             vt[((size_t)h * 64 + d) * 4096 + n] = u;
        }
    }
}

// ---------------------------------------------------------------- flash attention
// Block = (head, 16 q-rows); 4 waves x 1024-wide KV quarters; online softmax
// (R9-verbatim max tracking). Lambda-deferral: per-lane l partials rescaled by
// row-uniform al, reduced once after the KV loop.
__global__ __launch_bounds__(256) void attn_kernel(
    const unsigned short* __restrict__ q, const unsigned short* __restrict__ k,
    const unsigned short* __restrict__ vt, const float* __restrict__ dist,
    const float* __restrict__ nis_p, unsigned short* __restrict__ att) {
    __shared__ char smem[16896];   // pbuf 4x(16x72)u16 | obuf+mlbuf
    int lane = threadIdx.x & 63, wave = threadIdx.x >> 6;
    int l16 = lane & 15, quad = lane >> 4;
    int h = blockIdx.x >> 8;
    int q0 = (blockIdx.x & 255) * 16;
    int kvbase = wave * 1024;
    float nis = *nis_p;
    const float scale = 0.125f;

    unsigned short* pb = (unsigned short*)smem + wave * 1152;   // 16 x 72

    const unsigned short* qbase = q + ((size_t)h * 4096 + q0 + l16) * 64 + quad * 8;
    bf16x8 qf0 = *(const bf16x8*)(qbase);
    bf16x8 qf1 = *(const bf16x8*)(qbase + 32);

    f32x4 o[4];
    float m[4], lam[4];
#pragma unroll
    for (int r = 0; r < 4; r++) {
        m[r] = -1e30f; lam[r] = 0.f;
        o[0][r] = 0.f; o[1][r] = 0.f; o[2][r] = 0.f; o[3][r] = 0.f;
    }

    for (int kv0 = kvbase; kv0 < kvbase + 1024; kv0 += 64) {
        f32x4 s[4];
#pragma unroll
        for (int cb = 0; cb < 4; cb++) {
            const unsigned short* kbase =
                k + ((size_t)h * 4096 + kv0 + cb * 16 + l16) * 64 + quad * 8;
            bf16x8 kf0 = *(const bf16x8*)(kbase);
            bf16x8 kf1 = *(const bf16x8*)(kbase + 32);
            f32x4 z = (f32x4){0.f, 0.f, 0.f, 0.f};
            z = MFMA16(qf0, kf0, z);
            z = MFMA16(qf1, kf1, z);
            s[cb] = z;
        }
#pragma unroll
        for (int r = 0; r < 4; r++) {
            const float* drow = dist + (size_t)(q0 + quad * 4 + r) * 4096 + kv0 + l16;
#pragma unroll
            for (int cb = 0; cb < 4; cb++)
                s[cb][r] = s[cb][r] * scale + drow[cb * 16] * nis;
        }
        // row max (R9-verbatim)
        float mt[4];
#pragma unroll
        for (int r = 0; r < 4; r++) {
            float v = fmaxf(fmaxf(s[0][r], s[1][r]), fmaxf(s[2][r], s[3][r]));
#pragma unroll
            for (int off = 1; off < 16; off <<= 1)
                v = fmaxf(v, __shfl_xor(v, off, 64));
            mt[r] = v;
        }
        float al[4];
#pragma unroll
        for (int r = 0; r < 4; r++) {
            float mn = fmaxf(m[r], mt[r]);
            al[r] = __expf(m[r] - mn);
            m[r] = mn;
        }
        // per-lane tile sums — NO shuffles here (lambda-deferral)
        float ts[4] = {0.f, 0.f, 0.f, 0.f};
#pragma unroll
        for (int cb = 0; cb < 4; cb++)
#pragma unroll
            for (int r = 0; r < 4; r++) {
                float p = __expf(s[cb][r] - m[r]);
                ts[r] += p;
                s[cb][r] = p;
            }
#pragma unroll
        for (int r = 0; r < 4; r++) {
            lam[r] = lam[r] * al[r] + ts[r];
            o[0][r] *= al[r]; o[1][r] *= al[r]; o[2][r] *= al[r]; o[3][r] *= al[r];
        }
        // P (C-layout) -> LDS -> A-operand layout
#pragma unroll
        for (int cb = 0; cb < 4; cb++)
#pragma unroll
            for (int r = 0; r < 4; r++)
                pb[(quad * 4 + r) * 72 + cb * 16 + l16] = f2b(s[cb][r]);
        asm volatile("s_waitcnt lgkmcnt(0)" ::: "memory");
        bf16x8 pf0 = *(const bf16x8*)(pb + l16 * 72 + quad * 8);
        bf16x8 pf1 = *(const bf16x8*)(pb + l16 * 72 + 32 + quad * 8);
#pragma unroll
        for (int db = 0; db < 4; db++) {
            const unsigned short* vbase =
                vt + ((size_t)h * 64 + db * 16 + l16) * 4096 + kv0 + quad * 8;
            bf16x8 vf0 = *(const bf16x8*)(vbase);
            bf16x8 vf1 = *(const bf16x8*)(vbase + 32);
            o[db] = MFMA16(pf0, vf0, o[db]);
            o[db] = MFMA16(pf1, vf1, o[db]);
        }
    }

    // deferred row-sum reduction: once, not per tile
#pragma unroll
    for (int r = 0; r < 4; r++)
#pragma unroll
        for (int off = 1; off < 16; off <<= 1)
            lam[r] += __shfl_xor(lam[r], off, 64);

    // -------- block-level merge of 4 KV-chunk partials (R9-verbatim)
    __syncthreads();                       // all waves done with pbuf
    float* obuf = (float*)smem;            // [4 chunk][16 row][64 d]
    float* mlbuf = (float*)(smem + 16384); // [4 chunk][16 row][2]
#pragma unroll
    for (int db = 0; db < 4; db++)
#pragma unroll
        for (int r = 0; r < 4; r++)
            obuf[(wave * 16 + quad * 4 + r) * 64 + db * 16 + l16] = o[db][r];
    if (l16 == 0)
#pragma unroll
        for (int r = 0; r < 4; r++) {
            mlbuf[(wave * 16 + quad * 4 + r) * 2 + 0] = m[r];
            mlbuf[(wave * 16 + quad * 4 + r) * 2 + 1] = lam[r];
        }
    __syncthreads();

    int d = threadIdx.x & 63;
#pragma unroll
    for (int i = 0; i < 4; i++) {
        int row = (threadIdx.x >> 6) * 4 + i;
        float m0c = mlbuf[(0 * 16 + row) * 2], m1c = mlbuf[(1 * 16 + row) * 2];
        float m2c = mlbuf[(2 * 16 + row) * 2], m3c = mlbuf[(3 * 16 + row) * 2];
        float M = fmaxf(fmaxf(m0c, m1c), fmaxf(m2c, m3c));
        float e0 = __expf(m0c - M), e1 = __expf(m1c - M);
        float e2 = __expf(m2c - M), e3 = __expf(m3c - M);
        float L = mlbuf[(0 * 16 + row) * 2 + 1] * e0 + mlbuf[(1 * 16 + row) * 2 + 1] * e1
                + mlbuf[(2 * 16 + row) * 2 + 1] * e2 + mlbuf[(3 * 16 + row) * 2 + 1] * e3;
        float O = obuf[(0 * 16 + row) * 64 + d] * e0 + obuf[(1 * 16 + row) * 64 + d] * e1
                + obuf[(2 * 16 + row) * 64 + d] * e2 + obuf[(3 * 16 + row) * 64 + d] * e3;
        att[(size_t)(q0 + row) * 512 + h * 64 + d] = f2b(O / L);
    }
}

// ---------------------------------------------------------------- output GEMM (fp32 store)
__global__ __launch_bounds__(256) void out_gemm(
    const unsigned short* __restrict__ att, const unsigned short* __restrict__ w,
    const float* __restrict__ b, float* __restrict__ out) {
    int lane = threadIdx.x & 63, wave = threadIdx.x >> 6;
    int l16 = lane & 15, quad = lane >> 4;
    int m0 = blockIdx.y * 64 + wave * 16;
    int n0 = blockIdx.x * 64;

    const unsigned short* arow = att + (size_t)(m0 + l16) * 512 + quad * 8;
    f32x4 acc[4];
#pragma unroll
    for (int nb = 0; nb < 4; nb++) acc[nb] = (f32x4){0.f, 0.f, 0.f, 0.f};

    for (int k0 = 0; k0 < 512; k0 += 32) {
        bf16x8 af = *(const bf16x8*)(arow + k0);
#pragma unroll
        for (int nb = 0; nb < 4; nb++) {
            bf16x8 bf = *(const bf16x8*)(w + (size_t)(n0 + nb * 16 + l16) * 512 + k0 + quad * 8);
            acc[nb] = MFMA16(af, bf, acc[nb]);
        }
    }
#pragma unroll
    for (int nb = 0; nb < 4; nb++) {
        float bj = b[n0 + nb * 16 + l16];
#pragma unroll
        for (int r = 0; r < 4; r++)
            out[(size_t)(m0 + quad * 4 + r) * 512 + n0 + nb * 16 + l16] =
                acc[nb][r] + bj;
    }
}

extern "C" void kernel_launch(void* const* d_in, const int* in_sizes, int n_in,
                              void* d_out, int out_size, void* d_ws, size_t ws_size,
                              hipStream_t stream) {
    const float* x    = (const float*)d_in[0];
    const float* lat  = (const float*)d_in[1];
    const float* lon  = (const float*)d_in[2];
    const float* wqkv = (const float*)d_in[3];
    const float* bqkv = (const float*)d_in[4];
    const float* wout = (const float*)d_in[5];
    const float* bout = (const float*)d_in[6];
    float* out = (float*)d_out;

    char* ws = (char*)d_ws;
    float* dist        = (float*)ws;                                  // 64 MiB
    double* partials   = (double*)(ws + 67108864);                    // 64 KiB
    float* nis         = (float*)(ws + 67108864 + 65536);             // 64 B
    unsigned short* q  = (unsigned short*)(ws + 67108864 + 65600);
    unsigned short* k  = q  + (size_t)8 * 4096 * 64;   // 4 MiB each
    unsigned short* vt = k  + (size_t)8 * 4096 * 64;
    unsigned short* att = vt + (size_t)8 * 4096 * 64;
    unsigned short* xb  = att + (size_t)4096 * 512;
    unsigned short* wqb = xb  + (size_t)4096 * 512;
    unsigned short* wob = wqb + (size_t)1536 * 512;

    cvt_kernel<<<2048, 256, 0, stream>>>(x, xb, 4096 * 512);
    cvt_kernel<<<768, 256, 0, stream>>>(wqkv, wqb, 1536 * 512);
    cvt_kernel<<<256, 256, 0, stream>>>(wout, wob, 512 * 512);
    dist_kernel<<<4096, 256, 0, stream>>>(lat, lon, dist, partials);
    stats_kernel<<<1, 256, 0, stream>>>(partials, nis);
    qkv_gemm<<<dim3(24, 64), 256, 0, stream>>>(xb, wqb, bqkv, q, k, vt);
    attn_kernel<<<2048, 256, 0, stream>>>(q, k, vt, dist, nis, att);
    out_gemm<<<dim3(8, 64), 256, 0, stream>>>(att, wob, bout, out);
}